// Round 1
// baseline (69.193 us; speedup 1.0000x reference)
//
#include <hip/hip_runtime.h>
#include <stdint.h>

// B,T,C = 2,768,64; N_HEAD=64 -> head_dim=1; fp32.
// R20: full fusion. rocprof showed the timed region is dominated by the
// harness's 256 MiB workspace poison (~40us @83% HBM peak); our two kernels
// are each sub-40us and mostly dispatch latency + a qs/ks/vs/MOM global
// round-trip. Fuse: 256 blocks (half,h,b) x 384 thr = 1 block/CU, 6 waves.
// Phase 1: each wave projects+moments 2 j-blocks (k-dot redundancy x2 is
// ~0.2us chip-wide, trivial). Phase 2: combL per tile. Phase 3: wave w owns
// tile w; each THREAD owns a full row (64-j exact diag + 4 Taylor moment
// evals) -> no cross-wave reduce, no workspace, single dispatch.
constexpr int Tc = 768;
constexpr int Hc = 64;
constexpr int Bc = 2;
constexpr int NT = 12;                 // 64-wide j-blocks per sequence
constexpr float LOG2E = 1.44269504088896f;
constexpr float LN2   = 0.69314718056f;

typedef float v2f __attribute__((ext_vector_type(2)));
typedef float v4f __attribute__((ext_vector_type(4)));

__global__ __launch_bounds__(384) void fused_attn_kernel(
    const float* __restrict__ x, const float* __restrict__ W,
    const float* __restrict__ vtmp, const float* __restrict__ ptmp,
    float* __restrict__ out)
{
    const int tid  = threadIdx.x;
    const int lane = tid & 63;
    const int w    = __builtin_amdgcn_readfirstlane(tid >> 6);  // 0..5
    const int half = blockIdx.x;                 // 0..1 (6 row-tiles each)
    const int h    = blockIdx.y;
    const int b    = blockIdx.z;

    __shared__ float momL[NT * 32];              // 1.5 KB
    __shared__ float kdL[384], vdL[384], qL[384];// 4.5 KB (our half's tiles)
    __shared__ float combL[6 * 32];              // per-tile collapsed moments

    const float slope2 = exp2f(-0.125f * (float)(h + 1)) * LOG2E;
    const float vscale = vtmp[h] * ptmp[h];
    const float lf = exp2f(slope2 * (float)(lane - 63));   // 2^{s(j-eB)} <= 1
    const float* __restrict__ wq = W + h * 64;
    const float* __restrict__ wk = W + (64 + h) * 64;

    // ---- phase 1: projection + per-j-block moments (wave w -> blocks w, w+6)
    for (int it = 0; it < 2; ++it) {
        const int Bj = it * 6 + w;               // j-block 0..11
        const int p  = Bj * 64 + lane;           // sequence position
        const v4f* xp = (const v4f*)(x + ((size_t)(b * Tc + p)) * 64);
        float aq = 0.f, ak = 0.f;
#pragma unroll
        for (int c = 0; c < 16; ++c) {
            v4f u = xp[c];
            aq = fmaf(u.x, wq[4*c],   aq);  ak = fmaf(u.x, wk[4*c],   ak);
            aq = fmaf(u.y, wq[4*c+1], aq);  ak = fmaf(u.y, wk[4*c+1], ak);
            aq = fmaf(u.z, wq[4*c+2], aq);  ak = fmaf(u.z, wk[4*c+2], ak);
            aq = fmaf(u.w, wq[4*c+3], aq);  ak = fmaf(u.w, wk[4*c+3], ak);
        }
        const float vv = x[((size_t)(b * Tc + p)) * 64 + h] * vscale;
        if (it == half) {                        // wave-uniform branch
            const int loc = w * 64 + lane;       // local row in our half
            qL[loc]  = aq * LOG2E;
            kdL[loc] = ak;
            vdL[loc] = vv;
        }

        float km[8];
        km[0] = 1.f;
#pragma unroll
        for (int m = 1; m < 8; ++m) km[m] = km[m - 1] * ak;

        float r[32];
#pragma unroll
        for (int m = 0; m < 8; ++m) {
            const float kl2 = km[m] * lf;
            r[m]      = km[m];
            r[8 + m]  = km[m] * vv;
            r[16 + m] = kl2;
            r[24 + m] = kl2 * vv;
        }
        // reduce-to-lane-63 (validated R18 pattern)
#define DPP_PASS(CTRL)                                                        \
    _Pragma("unroll")                                                         \
    for (int ii = 0; ii < 32; ++ii)                                           \
        r[ii] += __int_as_float(__builtin_amdgcn_update_dpp(                  \
            0, __float_as_int(r[ii]), CTRL, 0xf, 0xf, true));
        DPP_PASS(0x111)
        DPP_PASS(0x112)
        DPP_PASS(0x114)
        DPP_PASS(0x118)
        DPP_PASS(0x142)
        DPP_PASS(0x143)
#undef DPP_PASS

        if (lane == 63) {
            float* mp = momL + Bj * 32;
#pragma unroll
            for (int m = 0; m < 8; ++m) {
                v4f s4 = { r[4*m], r[4*m+1], r[4*m+2], r[4*m+3] };
                *(v4f*)(mp + 4 * m) = s4;
            }
        }
    }
    __syncthreads();

    // ---- phase 2: collapse blocks into per-tile comb (192 threads) ----
    if (tid < 192) {
        const int lt  = tid >> 5;                // local tile 0..5
        const int idx = tid & 31;
        const int rt  = half * 6 + lt;
        const int m16 = idx & 15;
        float acc = 0.f;
        if (idx < 16) {                          // future suffix
            for (int B = rt + 1; B < NT; ++B)
                acc += momL[B * 32 + m16];
        } else {                                 // weighted past prefix
            for (int B = 0; B < rt; ++B)
                acc = fmaf(exp2f(slope2 * (float)(64 * (B - rt) + 63)),
                           momL[B * 32 + 16 + m16], acc);  // underflow->0 far
        }
        combL[lt * 32 + idx] = acc;
    }
    __syncthreads();

    // ---- phase 3: wave w owns tile (half*6+w); each thread owns one row ----
    const int rt = half * 6 + w;
    const int i  = rt * 64 + lane;
    const float q2 = qL[w * 64 + lane];          // q * log2e

    // Taylor p_m = q^m/m!  (q natural = q2*ln2)
    const float z  = q2 * LN2;
    const float p1 = z;
    const float p2 = z * p1 * 0.5f;
    const float p3 = z * p2 * (1.f / 3.f);
    const float p4 = z * p3 * 0.25f;
    const float p5 = z * p4 * 0.2f;
    const float p6 = z * p5 * (1.f / 6.f);
    const float p7 = z * p6 * (1.f / 7.f);

    const float* __restrict__ cb = combL + w * 32;  // broadcast LDS reads
    float sf = cb[0];
    sf = fmaf(p1, cb[1], sf); sf = fmaf(p2, cb[2], sf);
    sf = fmaf(p3, cb[3], sf); sf = fmaf(p4, cb[4], sf);
    sf = fmaf(p5, cb[5], sf); sf = fmaf(p6, cb[6], sf);
    sf = fmaf(p7, cb[7], sf);
    float af = cb[8];
    af = fmaf(p1, cb[9],  af); af = fmaf(p2, cb[10], af);
    af = fmaf(p3, cb[11], af); af = fmaf(p4, cb[12], af);
    af = fmaf(p5, cb[13], af); af = fmaf(p6, cb[14], af);
    af = fmaf(p7, cb[15], af);
    float sp = cb[16];
    sp = fmaf(p1, cb[17], sp); sp = fmaf(p2, cb[18], sp);
    sp = fmaf(p3, cb[19], sp); sp = fmaf(p4, cb[20], sp);
    sp = fmaf(p5, cb[21], sp); sp = fmaf(p6, cb[22], sp);
    sp = fmaf(p7, cb[23], sp);
    float ap = cb[24];
    ap = fmaf(p1, cb[25], ap); ap = fmaf(p2, cb[26], ap);
    ap = fmaf(p3, cb[27], ap); ap = fmaf(p4, cb[28], ap);
    ap = fmaf(p5, cb[29], ap); ap = fmaf(p6, cb[30], ap);
    ap = fmaf(p7, cb[31], ap);
    const float f = __builtin_amdgcn_exp2f(-slope2 * (float)lane); // 2^{s(r0-i)}
    float S = fmaf(f, sp, sf);
    float A = fmaf(f, ap, af);

    // exact diagonal tile: all 64 j for this row (LDS broadcast reads)
    const float negl = -slope2 * (float)lane;
    const v2f* __restrict__ k2p = (const v2f*)kdL + w * 32;
    const v2f* __restrict__ v2p = (const v2f*)vdL + w * 32;
#pragma unroll
    for (int u = 0; u < 32; ++u) {
        v2f k2 = k2p[u];
        v2f v2 = v2p[u];
        const float t0 = fminf(fmaf(slope2, (float)(2 * u),     negl), 0.f);
        const float t1 = fminf(fmaf(slope2, (float)(2 * u + 1), negl), 0.f);
        const float e0 = __builtin_amdgcn_exp2f(fmaf(q2, k2.x, t0));
        const float e1 = __builtin_amdgcn_exp2f(fmaf(q2, k2.y, t1));
        S += e0 + e1;
        A = fmaf(e0, v2.x, A);
        A = fmaf(e1, v2.y, A);
    }

    out[((size_t)(b * Tc + i)) * 64 + h] = A * __builtin_amdgcn_rcpf(S);
}

extern "C" void kernel_launch(void* const* d_in, const int* in_sizes, int n_in,
                              void* d_out, int out_size, void* d_ws, size_t ws_size,
                              hipStream_t stream) {
    const float* x    = (const float*)d_in[0];
    const float* W    = (const float*)d_in[1];
    const float* vtmp = (const float*)d_in[2];
    const float* ptmp = (const float*)d_in[3];
    float* out = (float*)d_out;
    (void)d_ws; (void)ws_size;

    fused_attn_kernel<<<dim3(2, Hc, Bc), 384, 0, stream>>>(
        x, W, vtmp, ptmp, out);
}

// Round 2
// 67.385 us; speedup vs baseline: 1.0268x; 1.0268x over previous
//
#include <hip/hip_runtime.h>
#include <stdint.h>

// B,T,C = 2,768,64; N_HEAD=64 -> head_dim=1; fp32.
// R21: revert to two-kernel R19 structure (best known, 66.8us). R20's fusion
// A/B proved: poison fill (40us, 83% HBM) is unconditional; dispatch g~1-2us;
// phase-1 ~4us chip; fixed overhead ~20us. Only lever left: attn structure.
// attn -> single-wave 64-thr blocks: full row per thread (64-j diag), comb
// evals per lane, no psum/pacc cross-wave reduce, barriers elide (1-wave WG).
// proj_mom byte-identical to R19 (validated).
constexpr int Tc = 768;
constexpr int Hc = 64;
constexpr int Bc = 2;
constexpr int NT = 12;                 // 64-wide j-blocks per sequence
constexpr float LOG2E = 1.44269504088896f;
constexpr float LN2   = 0.69314718056f;
constexpr size_t SLAB = (size_t)Bc * Hc * Tc;        // 98304 floats

typedef float v2f __attribute__((ext_vector_type(2)));
typedef float v4f __attribute__((ext_vector_type(4)));

// ---------------------------------------------------------------------------
// Kernel A: projection + per-block moments (R18/R19, measured-adequate).
// grid (24, 64) x 64 thr = 1536 single-wave blocks = 6 waves/CU.
//   MOM[bh][B][0..7]=sum k^m, [8..15]=sum k^m v,
//            [16..23]=sum k^m 2^{s(j-eB)}, [24..31]=... * v   (eB=B*64+63)
// ---------------------------------------------------------------------------
__global__ __launch_bounds__(64) void proj_mom_kernel(
    const float* __restrict__ x, const float* __restrict__ W,
    const float* __restrict__ vtmp, const float* __restrict__ ptmp,
    float* __restrict__ qs, float* __restrict__ ks, float* __restrict__ vs,
    float* __restrict__ MOM)
{
    const int lane = threadIdx.x & 63;
    const int bx   = blockIdx.x;                 // 0..23 = b*12 + B
    const int b    = bx / NT;
    const int B    = bx - b * NT;
    const int t    = B * 64 + lane;
    const int g    = bx * 64 + lane;             // row in x (b*768 + t)
    const int h    = blockIdx.y;                 // block-uniform
    const int bh   = b * Hc + h;

    const v4f* xp = (const v4f*)(x + (size_t)g * 64);
    const float* __restrict__ wq = W + h * 64;
    const float* __restrict__ wk = W + (64 + h) * 64;
    float aq = 0.f, ak = 0.f;
#pragma unroll
    for (int c = 0; c < 16; ++c) {
        v4f u = xp[c];
        aq = fmaf(u.x, wq[4*c],   aq);  ak = fmaf(u.x, wk[4*c],   ak);
        aq = fmaf(u.y, wq[4*c+1], aq);  ak = fmaf(u.y, wk[4*c+1], ak);
        aq = fmaf(u.z, wq[4*c+2], aq);  ak = fmaf(u.z, wk[4*c+2], ak);
        aq = fmaf(u.w, wq[4*c+3], aq);  ak = fmaf(u.w, wk[4*c+3], ak);
    }
    const float vv = x[(size_t)g * 64 + h] * vtmp[h] * ptmp[h];
    const size_t o = (size_t)bh * Tc + t;        // lane-coalesced
    qs[o] = aq * LOG2E;
    ks[o] = ak;
    vs[o] = vv;

    const float slope2 = exp2f(-0.125f * (float)(h + 1)) * LOG2E;
    const float lf = exp2f(slope2 * (float)(lane - 63));   // 2^{s(j-eB)} <= 1

    float km[8];
    km[0] = 1.f;
#pragma unroll
    for (int m = 1; m < 8; ++m) km[m] = km[m - 1] * ak;

    float r[32];
#pragma unroll
    for (int m = 0; m < 8; ++m) {
        const float kl2 = km[m] * lf;
        r[m]      = km[m];
        r[8 + m]  = km[m] * vv;
        r[16 + m] = kl2;
        r[24 + m] = kl2 * vv;
    }
#define DPP_PASS(CTRL)                                                        \
    _Pragma("unroll")                                                         \
    for (int ii = 0; ii < 32; ++ii)                                           \
        r[ii] += __int_as_float(__builtin_amdgcn_update_dpp(                  \
            0, __float_as_int(r[ii]), CTRL, 0xf, 0xf, true));
    DPP_PASS(0x111)
    DPP_PASS(0x112)
    DPP_PASS(0x114)
    DPP_PASS(0x118)
    DPP_PASS(0x142)
    DPP_PASS(0x143)
#undef DPP_PASS

    if (lane == 63) {
        float* mp = MOM + ((size_t)bh * NT + B) * 32;
#pragma unroll
        for (int m = 0; m < 8; ++m) {
            v4f s4 = { r[4*m], r[4*m+1], r[4*m+2], r[4*m+3] };
            *(v4f*)(mp + 4 * m) = s4;
        }
    }
}

// ---------------------------------------------------------------------------
// Kernel B (R21): single-wave attention. grid (12,64,2) x 64 thr = 1536
// waves, 6 waves/CU. Each thread owns one full row:
//   off-diag  = suffix-eval + 2^{-s*lane} * prefix-eval   (Taylor, comb[32])
//   diagonal  = exact 64-j exp2 loop over LDS-broadcast kd/vd
// No cross-wave reduction; __syncthreads elides to waitcnt (1-wave WG).
// ---------------------------------------------------------------------------
__global__ __launch_bounds__(64) void attn_kernel(
    const float* __restrict__ qs, const float* __restrict__ ks,
    const float* __restrict__ vs, const float* __restrict__ MOM,
    float* __restrict__ out)
{
    const int lane = threadIdx.x & 63;
    const int rt   = blockIdx.x;     // 0..11
    const int h    = blockIdx.y;
    const int b    = blockIdx.z;
    const int bh   = b * Hc + h;

    __shared__ float momL[NT * 32];              // 1.5 KB
    __shared__ float kd[64], vd[64];
    __shared__ float comb[32];

    // ---- stage: moments (3 x v2f per lane) + diag k/v (coalesced) ----
    {
        const v2f* __restrict__ mbp2 = (const v2f*)(MOM + (size_t)bh * (NT * 32));
        v2f* __restrict__ mL2 = (v2f*)momL;
#pragma unroll
        for (int k = 0; k < 3; ++k)
            mL2[lane + 64 * k] = mbp2[lane + 64 * k];
        kd[lane] = ks[(size_t)bh * Tc + rt * 64 + lane];
        vd[lane] = vs[(size_t)bh * Tc + rt * 64 + lane];
    }
    const float slope2 = exp2f(-0.125f * (float)(h + 1)) * LOG2E;
    __syncthreads();

    // ---- collapse blocks: lanes 0..31 build comb ----
    if (lane < 32) {
        const int grp = lane >> 4;       // 0 = future suffix, 1 = past prefix
        const int m16 = lane & 15;
        float acc = 0.f;
        if (grp == 0) {
            for (int B = rt + 1; B < NT; ++B)
                acc += momL[B * 32 + m16];
        } else {
            for (int B = 0; B < rt; ++B)
                acc = fmaf(exp2f(slope2 * (float)(64 * (B - rt) + 63)),
                           momL[B * 32 + 16 + m16], acc);   // underflow->0 far
        }
        comb[lane] = acc;
    }
    __syncthreads();

    // ---- per-row state ----
    const int i = rt * 64 + lane;
    const float q2 = qs[(size_t)bh * Tc + i];    // q * log2e (coalesced)

    // Taylor p_m = q^m/m!  (q natural = q2*ln2)
    const float z  = q2 * LN2;
    const float p1 = z;
    const float p2 = z * p1 * 0.5f;
    const float p3 = z * p2 * (1.f / 3.f);
    const float p4 = z * p3 * 0.25f;
    const float p5 = z * p4 * 0.2f;
    const float p6 = z * p5 * (1.f / 6.f);
    const float p7 = z * p6 * (1.f / 7.f);

    // off-diagonal: one suffix eval + one weighted prefix eval (all lanes)
    float sf = comb[0];
    sf = fmaf(p1, comb[1], sf); sf = fmaf(p2, comb[2], sf);
    sf = fmaf(p3, comb[3], sf); sf = fmaf(p4, comb[4], sf);
    sf = fmaf(p5, comb[5], sf); sf = fmaf(p6, comb[6], sf);
    sf = fmaf(p7, comb[7], sf);
    float af = comb[8];
    af = fmaf(p1, comb[9],  af); af = fmaf(p2, comb[10], af);
    af = fmaf(p3, comb[11], af); af = fmaf(p4, comb[12], af);
    af = fmaf(p5, comb[13], af); af = fmaf(p6, comb[14], af);
    af = fmaf(p7, comb[15], af);
    float sp = comb[16];
    sp = fmaf(p1, comb[17], sp); sp = fmaf(p2, comb[18], sp);
    sp = fmaf(p3, comb[19], sp); sp = fmaf(p4, comb[20], sp);
    sp = fmaf(p5, comb[21], sp); sp = fmaf(p6, comb[22], sp);
    sp = fmaf(p7, comb[23], sp);
    float ap = comb[24];
    ap = fmaf(p1, comb[25], ap); ap = fmaf(p2, comb[26], ap);
    ap = fmaf(p3, comb[27], ap); ap = fmaf(p4, comb[28], ap);
    ap = fmaf(p5, comb[29], ap); ap = fmaf(p6, comb[30], ap);
    ap = fmaf(p7, comb[31], ap);
    const float f = __builtin_amdgcn_exp2f(-slope2 * (float)lane); // 2^{s(r0-i)}
    float S = fmaf(f, sp, sf);
    float A = fmaf(f, ap, af);

    // ---- exact diagonal: all 64 j for this row (LDS broadcast reads) ----
    const float negl = -slope2 * (float)lane;
    const v2f* __restrict__ k2p = (const v2f*)kd;
    const v2f* __restrict__ v2p = (const v2f*)vd;
#pragma unroll
    for (int u = 0; u < 32; ++u) {
        v2f k2 = k2p[u];
        v2f v2 = v2p[u];
        const float t0 = fminf(fmaf(slope2, (float)(2 * u),     negl), 0.f);
        const float t1 = fminf(fmaf(slope2, (float)(2 * u + 1), negl), 0.f);
        const float e0 = __builtin_amdgcn_exp2f(fmaf(q2, k2.x, t0));
        const float e1 = __builtin_amdgcn_exp2f(fmaf(q2, k2.y, t1));
        S += e0 + e1;
        A = fmaf(e0, v2.x, A);
        A = fmaf(e1, v2.y, A);
    }

    out[((size_t)(b * Tc + i)) * 64 + h] = A * __builtin_amdgcn_rcpf(S);
}

extern "C" void kernel_launch(void* const* d_in, const int* in_sizes, int n_in,
                              void* d_out, int out_size, void* d_ws, size_t ws_size,
                              hipStream_t stream) {
    const float* x    = (const float*)d_in[0];
    const float* W    = (const float*)d_in[1];
    const float* vtmp = (const float*)d_in[2];
    const float* ptmp = (const float*)d_in[3];
    float* out = (float*)d_out;

    float* qsl = (float*)d_ws;
    float* ksl = qsl + SLAB;
    float* vsl = ksl + SLAB;
    float* mom = vsl + SLAB;           // [bh][12][32]

    proj_mom_kernel<<<dim3(24, Hc), 64, 0, stream>>>(
        x, W, vtmp, ptmp, qsl, ksl, vsl, mom);
    attn_kernel<<<dim3(NT, Hc, Bc), 64, 0, stream>>>(
        qsl, ksl, vsl, mom, out);
}